// Round 7
// baseline (216.487 us; speedup 1.0000x reference)
//
#include <hip/hip_runtime.h>

// Problem constants (reference: B=32, L=64, C=4)
#define BB 32
#define LL 64
#define LC 256
#define NPAIR 2016
#define PPB 2                 // pairs per block
#define NBLK (NPAIR / PPB)    // 1008 blocks <= 1024 co-residency @ 4/CU
#define WSTR 1024             // ws partial stride per b (floats)
#define FLAG_OFF (BB * WSTR)  // float index where flag region starts
#define MAGIC0 0x5A17C0DEu
#define MAGIC1 0x0DDC0FFEu

// v5 (resubmit; round-6 never acquired a GPU). Single NON-cooperative
// dispatch. Round-5 evidence: cg grid.sync() costs ~100us on MI355X
// (fused_kernel dur 105us, VALUBusy 1.9%) -- dead. Timing model consistent
// across v2/v3/v4: dur ~= 2x41us unconditional ws poison fills + ~10-15us
// gaps + our kernels. Controllable budget ~15-20us. ONE dispatch via a
// lock-free handshake:
//   - all 1008 blocks: v2's coalesced float4 theta3 row gather (2 pairs),
//     publish 32 per-b partials (agent-scope relaxed stores) + a 2-dword
//     magic flag (agent-scope release). Poison cannot forge the flag;
//     inputs are iteration-invariant so even stale flags yield identical
//     (correct) partials.
//   - blocks 0..31: additionally reduce 1008 partials for batch b=j,
//     spin-waiting per flag with acquire loads + s_sleep backoff, add
//     theta1 (argmax from x) + theta0, plain store to out.
// No deadlock: 1008 blocks co-resident at __launch_bounds__(256,4).
__global__ __launch_bounds__(256, 4) void fused1(
    const float* __restrict__ x, const float* __restrict__ t0,
    const float* __restrict__ t1, const float* __restrict__ t2,
    const float* __restrict__ t3, float* __restrict__ ws,
    float* __restrict__ out)
{
    const int tid = threadIdx.x;
    const int j = blockIdx.x;
    unsigned int* flags = (unsigned int*)(ws + FLAG_OFF);
    __shared__ float wsum[4];

    // ---------------- worker phase: 2 pairs ----------------
    {
        const int b = tid >> 3, k = tid & 7;
        const float4* __restrict__ x4 = (const float4*)x + b * 64;

        // codes for my 8 w's (w = 8m+k): once per block, reused across pairs
        int c[8];
#pragma unroll
        for (int m = 0; m < 8; ++m) {
            float4 f = x4[8 * m + k];
            int ci = 0; float best = f.x;
            if (f.y > best) { best = f.y; ci = 1; }
            if (f.z > best) { best = f.z; ci = 2; }
            if (f.w > best) { best = f.w; ci = 3; }
            c[m] = ci;
        }

        // decode first pair index t = v*(v-1)/2 + u for this block
        const int tp0 = j * PPB;
        int v = (int)((1.0f + sqrtf(8.0f * (float)tp0 + 1.0f)) * 0.5f);
        while (v * (v - 1) / 2 > tp0) --v;
        while ((v + 1) * v / 2 <= tp0) ++v;
        int u = tp0 - v * (v - 1) / 2;

        float acc = 0.0f;
#pragma unroll
        for (int i = 0; i < PPB; ++i) {
            float4 fu = x4[u], fv = x4[v];   // block-uniform, L1 broadcast
            int cu = 0; { float bst = fu.x;
                if (fu.y > bst) { bst = fu.y; cu = 1; }
                if (fu.z > bst) { bst = fu.z; cu = 2; }
                if (fu.w > bst) { bst = fu.w; cu = 3; } }
            int cv = 0; { float bst = fv.x;
                if (fv.y > bst) { bst = fv.y; cv = 1; }
                if (fv.z > bst) { bst = fv.z; cv = 2; }
                if (fv.w > bst) { bst = fv.w; cv = 3; } }
            const int pu = 4 * u + cu, pv = 4 * v + cv;

            const float4* __restrict__ row4 =
                (const float4*)(t3 + ((size_t)pu << 16) + ((size_t)pv << 8));
            if (k == 0) acc += t2[pu * LC + pv];   // theta2 term

#pragma unroll
            for (int m = 0; m < 8; ++m) {
                const int w = 8 * m + k;
                float4 f = row4[w];                 // coalesced 16B, in-bounds
                const int ci = c[m];
                float lo = (ci & 1) ? f.y : f.x;    // cndmask chain
                float hi = (ci & 1) ? f.w : f.z;
                float val = (ci & 2) ? hi : lo;
                acc += (w > v) ? val : 0.0f;        // strict-triangle mask
            }

            ++u; if (u == v) { u = 0; ++v; }        // next pair
        }

        // width-8 shuffle reduce over k, publish per-(block,b) partial
        acc += __shfl_down(acc, 4, 8);
        acc += __shfl_down(acc, 2, 8);
        acc += __shfl_down(acc, 1, 8);
        if (k == 0)
            __hip_atomic_store(&ws[b * WSTR + j], acc,
                               __ATOMIC_RELAXED, __HIP_MEMORY_SCOPE_AGENT);
    }
    __threadfence();       // device-scope: order value stores before flag
    __syncthreads();       // all lanes' stores issued before tid0's flag
    if (tid == 0) {
        __hip_atomic_store(&flags[2 * j], MAGIC0 ^ (unsigned)j,
                           __ATOMIC_RELEASE, __HIP_MEMORY_SCOPE_AGENT);
        __hip_atomic_store(&flags[2 * j + 1], MAGIC1 + (unsigned)j,
                           __ATOMIC_RELEASE, __HIP_MEMORY_SCOPE_AGENT);
    }

    if (j >= BB) return;

    // ---------------- reducer phase: blocks 0..31, b = j ----------------
    {
        const int b = j;
        float s = 0.0f;
        for (int p = tid; p < NBLK; p += 256) {
            for (;;) {
                unsigned f0 = __hip_atomic_load(&flags[2 * p],
                                  __ATOMIC_ACQUIRE, __HIP_MEMORY_SCOPE_AGENT);
                unsigned f1 = __hip_atomic_load(&flags[2 * p + 1],
                                  __ATOMIC_ACQUIRE, __HIP_MEMORY_SCOPE_AGENT);
                if (f0 == (MAGIC0 ^ (unsigned)p) &&
                    f1 == (MAGIC1 + (unsigned)p)) break;
                __builtin_amdgcn_s_sleep(1);
            }
            s += __hip_atomic_load(&ws[b * WSTR + p],
                                   __ATOMIC_RELAXED, __HIP_MEMORY_SCOPE_AGENT);
        }
        if (tid < LL) {
            float4 f = ((const float4*)x)[b * 64 + tid];
            int c = 0; float best = f.x;
            if (f.y > best) { best = f.y; c = 1; }
            if (f.z > best) { best = f.z; c = 2; }
            if (f.w > best) { best = f.w; c = 3; }
            s += t1[4 * tid + c];
        }
        for (int off = 32; off > 0; off >>= 1) s += __shfl_down(s, off, 64);
        if ((tid & 63) == 0) wsum[tid >> 6] = s;
        __syncthreads();
        if (tid == 0) out[b] = wsum[0] + wsum[1] + wsum[2] + wsum[3] + t0[0];
    }
}

extern "C" void kernel_launch(void* const* d_in, const int* in_sizes, int n_in,
                              void* d_out, int out_size, void* d_ws, size_t ws_size,
                              hipStream_t stream) {
    const float* x  = (const float*)d_in[0];  // (B, L*C)
    const float* t0 = (const float*)d_in[1];  // (1,)
    const float* t1 = (const float*)d_in[2];  // (L, C)
    const float* t2 = (const float*)d_in[3];  // (L, C, L, C)
    const float* t3 = (const float*)d_in[4];  // (L, C, L, C, L, C)
    float* out = (float*)d_out;               // (B, 1)
    float* ws  = (float*)d_ws;                // uses ~140 KB of workspace

    fused1<<<NBLK, 256, 0, stream>>>(x, t0, t1, t2, t3, ws, out);
}

// Round 8
// 107.033 us; speedup vs baseline: 2.0226x; 2.0226x over previous
//
#include <hip/hip_runtime.h>

// Problem constants (reference: B=32, L=64, C=4)
#define BB 32
#define LL 64
#define LC 256
#define NPAIR 2016
#define PPB 8                 // pairs per block
#define NBLK (NPAIR / PPB)    // 252 blocks ~ 1/CU, 4 waves/CU

// v6: two dispatches, minimal. Evidence:
//  - r5: cg grid.sync() ~100us on MI355X. r7: flag-spin handshake 138-151us
//    (8K spinning lanes congest the coherent fabric the workers' release
//    stores must traverse). Intra-dispatch cross-XCD sync is dead.
//  - dur ~= 83us (2x41us unconditional ws-poison fills) + gaps + kernels.
//    v2 (best, 105.6) spent ~22.6us controllable.
// Structure:
//  1) hipMemsetAsync(out, 0) -- ~2us graph-capturable memset replaces the
//     4us reduce kernel (zero-init for atomics; out is poisoned).
//  2) pair kernel, 252 blocks x 8 pairs: codes once per block (amortized
//     8x), coalesced float4 theta3 row gather, per-(block,b) reduction,
//     ONE atomicAdd per (block,b) -> 8064 atomics over 32 addrs (~1-2us
//     tail; v3's 16K-atomic tail was the regression there). Block 0 also
//     folds theta1 (argmax) + theta0 into its per-b partials.
__global__ __launch_bounds__(256) void pair_atomic(
    const float* __restrict__ x, const float* __restrict__ t0,
    const float* __restrict__ t1, const float* __restrict__ t2,
    const float* __restrict__ t3, float* __restrict__ out)
{
    const int tid = threadIdx.x;
    const int j = blockIdx.x;
    const int b = tid >> 3, k = tid & 7;
    const float4* __restrict__ x4 = (const float4*)x + b * 64;

    // codes for my 8 w's (w = 8m+k): once per block, reused across 8 pairs
    int c[8];
#pragma unroll
    for (int m = 0; m < 8; ++m) {
        float4 f = x4[8 * m + k];
        int ci = 0; float best = f.x;
        if (f.y > best) { best = f.y; ci = 1; }
        if (f.z > best) { best = f.z; ci = 2; }
        if (f.w > best) { best = f.w; ci = 3; }
        c[m] = ci;
    }

    float acc = 0.0f;
    if (j == 0) {
        // theta1 term, exactly once per b across the grid
#pragma unroll
        for (int m = 0; m < 8; ++m) acc += t1[4 * (8 * m + k) + c[m]];
    }

    // decode first pair index t = v*(v-1)/2 + u for this block
    const int tp0 = j * PPB;
    int v = (int)((1.0f + sqrtf(8.0f * (float)tp0 + 1.0f)) * 0.5f);
    while (v * (v - 1) / 2 > tp0) --v;
    while ((v + 1) * v / 2 <= tp0) ++v;
    int u = tp0 - v * (v - 1) / 2;

#pragma unroll
    for (int i = 0; i < PPB; ++i) {
        float4 fu = x4[u], fv = x4[v];   // block-uniform, L1 broadcast
        int cu = 0; { float bst = fu.x;
            if (fu.y > bst) { bst = fu.y; cu = 1; }
            if (fu.z > bst) { bst = fu.z; cu = 2; }
            if (fu.w > bst) { bst = fu.w; cu = 3; } }
        int cv = 0; { float bst = fv.x;
            if (fv.y > bst) { bst = fv.y; cv = 1; }
            if (fv.z > bst) { bst = fv.z; cv = 2; }
            if (fv.w > bst) { bst = fv.w; cv = 3; } }
        const int pu = 4 * u + cu, pv = 4 * v + cv;

        const float4* __restrict__ row4 =
            (const float4*)(t3 + ((size_t)pu << 16) + ((size_t)pv << 8));
        if (k == 0) acc += t2[pu * LC + pv];   // theta2 term

#pragma unroll
        for (int m = 0; m < 8; ++m) {
            const int w = 8 * m + k;
            float4 f = row4[w];                 // coalesced 16B, in-bounds
            const int ci = c[m];
            float lo = (ci & 1) ? f.y : f.x;    // cndmask chain, no scratch
            float hi = (ci & 1) ? f.w : f.z;
            float val = (ci & 2) ? hi : lo;
            acc += (w > v) ? val : 0.0f;        // strict-triangle mask
        }

        ++u; if (u == v) { u = 0; ++v; }        // next pair (triangular order)
    }

    // width-8 shuffle reduce over k, one atomic per (block, b)
    acc += __shfl_down(acc, 4, 8);
    acc += __shfl_down(acc, 2, 8);
    acc += __shfl_down(acc, 1, 8);
    if (k == 0) {
        float res = acc;
        if (j == 0) res += t0[0];               // theta0 once per b
        atomicAdd(&out[b], res);                // device-scope HW f32 atomic
    }
}

extern "C" void kernel_launch(void* const* d_in, const int* in_sizes, int n_in,
                              void* d_out, int out_size, void* d_ws, size_t ws_size,
                              hipStream_t stream) {
    const float* x  = (const float*)d_in[0];  // (B, L*C)
    const float* t0 = (const float*)d_in[1];  // (1,)
    const float* t1 = (const float*)d_in[2];  // (L, C)
    const float* t2 = (const float*)d_in[3];  // (L, C, L, C)
    const float* t3 = (const float*)d_in[4];  // (L, C, L, C, L, C)
    float* out = (float*)d_out;               // (B, 1)
    (void)d_ws; (void)ws_size;                // workspace unused

    hipMemsetAsync(d_out, 0, out_size, stream);   // zero poisoned out
    pair_atomic<<<NBLK, 256, 0, stream>>>(x, t0, t1, t2, t3, out);
}